// Round 1
// baseline (165.150 us; speedup 1.0000x reference)
//
#include <hip/hip_runtime.h>

#define EPS 1e-8f
#define THR 0.65f

constexpr int DIM  = 1024;
constexpr int SEQ  = 2048;
constexpr int NMEM = 131072;

// ws layout (floats):
//   [0..1023]   q accumulator -> becomes q mean
//   [1024]      q_norm (clamped)
//   [1026..1027] packed best (unsigned long long, 8B-aligned at byte 4104)

__global__ void init_kernel(float* __restrict__ ws) {
    int i = threadIdx.x;
    for (; i < 1028; i += 256) ws[i] = 0.0f;
}

// grid: 64 blocks x 256 threads. Each block sums 32 rows, each thread owns 4
// consecutive columns (float4). Coalesced 1 KiB/wave/iter.
__global__ void qsum_kernel(const float* __restrict__ query, float* __restrict__ ws) {
    const float4* q4 = (const float4*)query;   // [SEQ][256]
    int tid = threadIdx.x;
    int r0  = blockIdx.x * 32;
    float4 s = make_float4(0.f, 0.f, 0.f, 0.f);
    for (int r = 0; r < 32; ++r) {
        float4 v = q4[(size_t)(r0 + r) * 256 + tid];
        s.x += v.x; s.y += v.y; s.z += v.z; s.w += v.w;
    }
    float* dst = ws + tid * 4;
    atomicAdd(dst + 0, s.x);
    atomicAdd(dst + 1, s.y);
    atomicAdd(dst + 2, s.z);
    atomicAdd(dst + 3, s.w);
}

// 1 block x 256 threads: divide by SEQ, compute clamped ||q||.
__global__ void qfinal_kernel(float* __restrict__ ws) {
    __shared__ float red[4];
    int tid = threadIdx.x;
    float4 v = ((float4*)ws)[tid];
    const float inv = 1.0f / (float)SEQ;
    v.x *= inv; v.y *= inv; v.z *= inv; v.w *= inv;
    ((float4*)ws)[tid] = v;
    float ss = v.x * v.x + v.y * v.y + v.z * v.z + v.w * v.w;
    #pragma unroll
    for (int m = 32; m >= 1; m >>= 1) ss += __shfl_xor(ss, m);
    int lane = tid & 63, wid = tid >> 6;
    if (lane == 0) red[wid] = ss;
    __syncthreads();
    if (tid == 0) {
        float tot = red[0] + red[1] + red[2] + red[3];
        ws[1024] = fmaxf(sqrtf(tot), EPS);
    }
}

__device__ __forceinline__ unsigned int float_to_ordered(float f) {
    unsigned int b = __float_as_uint(f);
    return (b & 0x80000000u) ? ~b : (b | 0x80000000u);
}

// grid: 2048 blocks x 256 threads (4 waves). One wave per bank row,
// grid-stride. Dot + sum-of-squares in one pass (bank norms are free).
__launch_bounds__(256)
__global__ void sim_kernel(const float* __restrict__ bank, const float* __restrict__ ws,
                           unsigned long long* __restrict__ best) {
    __shared__ float qs[DIM];
    int tid = threadIdx.x;
    ((float4*)qs)[tid] = ((const float4*)ws)[tid];
    __syncthreads();
    float qn = ws[1024];

    int lane = tid & 63;
    int wid  = tid >> 6;
    int gw   = blockIdx.x * 4 + wid;
    int nw   = gridDim.x * 4;

    float bestSim = -1e30f;
    int   bestIdx = 0;
    const float4* qs4 = (const float4*)qs;

    for (int row = gw; row < NMEM; row += nw) {
        const float4* bp = (const float4*)(bank + (size_t)row * DIM);
        float dot = 0.f, ss = 0.f;
        #pragma unroll
        for (int it = 0; it < 4; ++it) {
            float4 b = bp[lane + it * 64];
            float4 q = qs4[lane + it * 64];
            dot += b.x * q.x + b.y * q.y + b.z * q.z + b.w * q.w;
            ss  += b.x * b.x + b.y * b.y + b.z * b.z + b.w * b.w;
        }
        #pragma unroll
        for (int m = 32; m >= 1; m >>= 1) {
            dot += __shfl_xor(dot, m);
            ss  += __shfl_xor(ss, m);
        }
        float bn  = fmaxf(sqrtf(ss), EPS);
        float sim = dot / (bn * qn);
        if (sim > bestSim) { bestSim = sim; bestIdx = row; }
    }
    if (lane == 0) {
        unsigned long long p =
            ((unsigned long long)float_to_ordered(bestSim) << 32) |
            (unsigned int)(~(unsigned int)bestIdx);   // ~idx: ties -> smaller idx
        atomicMax(best, p);
    }
}

// grid: 256 blocks x 256 threads (4 waves). One wave per output row.
__global__ void decode_kernel(const float* __restrict__ bank,
                              const float* __restrict__ w_dec,
                              const float* __restrict__ b_dec,
                              const unsigned long long* __restrict__ best,
                              float* __restrict__ out) {
    __shared__ float mem[DIM];
    int tid = threadIdx.x;

    unsigned long long p = *best;
    unsigned int u = (unsigned int)(p >> 32);
    unsigned int fb = (u & 0x80000000u) ? (u & 0x7FFFFFFFu) : ~u;
    float sim = __uint_as_float(fb);
    int idx   = (int)(~(unsigned int)(p & 0xFFFFFFFFu));

    ((float4*)mem)[tid] = ((const float4*)(bank + (size_t)idx * DIM))[tid];
    __syncthreads();

    bool ok  = sim > THR;
    int lane = tid & 63, wid = tid >> 6;
    int row  = blockIdx.x * 4 + wid;

    const float4* wp = (const float4*)(w_dec + (size_t)row * DIM);
    const float4* m4 = (const float4*)mem;
    float dot = 0.f;
    #pragma unroll
    for (int it = 0; it < 4; ++it) {
        float4 w = wp[lane + it * 64];
        float4 m = m4[lane + it * 64];
        dot += w.x * m.x + w.y * m.y + w.z * m.z + w.w * m.w;
    }
    #pragma unroll
    for (int m = 32; m >= 1; m >>= 1) dot += __shfl_xor(dot, m);

    if (lane == 0) out[row] = ok ? (dot + b_dec[row]) : 0.0f;
}

extern "C" void kernel_launch(void* const* d_in, const int* in_sizes, int n_in,
                              void* d_out, int out_size, void* d_ws, size_t ws_size,
                              hipStream_t stream) {
    const float* query = (const float*)d_in[0];
    const float* bank  = (const float*)d_in[1];
    const float* w_dec = (const float*)d_in[2];
    const float* b_dec = (const float*)d_in[3];
    float* out = (float*)d_out;
    float* ws  = (float*)d_ws;
    unsigned long long* best = (unsigned long long*)(ws + 1026);

    init_kernel<<<1, 256, 0, stream>>>(ws);
    qsum_kernel<<<64, 256, 0, stream>>>(query, ws);
    qfinal_kernel<<<1, 256, 0, stream>>>(ws);
    sim_kernel<<<2048, 256, 0, stream>>>(bank, ws, best);
    decode_kernel<<<256, 256, 0, stream>>>(bank, w_dec, b_dec, best, out);
}

// Round 2
// 111.831 us; speedup vs baseline: 1.4768x; 1.4768x over previous
//
#include <hip/hip_runtime.h>

#define EPS 1e-8f
#define THR 0.65f

constexpr int DIM  = 1024;
constexpr int SEQ  = 2048;
constexpr int NMEM = 131072;

constexpr int NCOPY     = 8;     // spread copies of the q accumulator
constexpr int SIM_BLKS  = 2048;  // sim grid; one best per block

// ws layout (float indices):
//   [0 .. 8192)        8 copies x 1024 q accumulators
//   [8192 .. 9216)     q mean
//   [9216]             q_norm (clamped)
//   [9218 .. 13314)    bests[2048] as u64 (byte 36872, 8-aligned)
//   [13314 .. 13316)   final packed best u64 (byte 53256, 8-aligned)
constexpr int WS_Q     = 8192;
constexpr int WS_QNORM = 9216;
constexpr int WS_BESTS = 9218;
constexpr int WS_FINAL = 13314;

__global__ void init_kernel(float* __restrict__ ws) {
    // zero the 8 accumulator copies: 8 blocks x 256 threads x float4
    ((float4*)ws)[blockIdx.x * 256 + threadIdx.x] = make_float4(0.f, 0.f, 0.f, 0.f);
}

// grid: 256 blocks x 256 threads. Block b sums rows [8b, 8b+8); thread t owns
// float4 column t. Atomics spread over NCOPY accumulator copies.
__global__ void qsum_kernel(const float* __restrict__ query, float* __restrict__ ws) {
    const float4* q4 = (const float4*)query;   // [SEQ][256]
    int tid = threadIdx.x;
    int r0  = blockIdx.x * 8;
    float4 s = make_float4(0.f, 0.f, 0.f, 0.f);
    #pragma unroll
    for (int r = 0; r < 8; ++r) {
        float4 v = q4[(size_t)(r0 + r) * 256 + tid];
        s.x += v.x; s.y += v.y; s.z += v.z; s.w += v.w;
    }
    float* dst = ws + (blockIdx.x & (NCOPY - 1)) * DIM + tid * 4;
    atomicAdd(dst + 0, s.x);
    atomicAdd(dst + 1, s.y);
    atomicAdd(dst + 2, s.z);
    atomicAdd(dst + 3, s.w);
}

// 1 block x 256 threads: fold copies, divide by SEQ, clamped ||q||.
__global__ void qfinal_kernel(float* __restrict__ ws) {
    __shared__ float red[4];
    int tid = threadIdx.x;
    float4 v = make_float4(0.f, 0.f, 0.f, 0.f);
    #pragma unroll
    for (int c = 0; c < NCOPY; ++c) {
        float4 p = ((float4*)ws)[c * 256 + tid];
        v.x += p.x; v.y += p.y; v.z += p.z; v.w += p.w;
    }
    const float inv = 1.0f / (float)SEQ;
    v.x *= inv; v.y *= inv; v.z *= inv; v.w *= inv;
    ((float4*)(ws + WS_Q))[tid] = v;
    float ss = v.x * v.x + v.y * v.y + v.z * v.z + v.w * v.w;
    #pragma unroll
    for (int m = 32; m >= 1; m >>= 1) ss += __shfl_xor(ss, m);
    int lane = tid & 63, wid = tid >> 6;
    if (lane == 0) red[wid] = ss;
    __syncthreads();
    if (tid == 0) {
        float tot = red[0] + red[1] + red[2] + red[3];
        ws[WS_QNORM] = fmaxf(sqrtf(tot), EPS);
    }
}

__device__ __forceinline__ unsigned int float_to_ordered(float f) {
    unsigned int b = __float_as_uint(f);
    return (b & 0x80000000u) ? ~b : (b | 0x80000000u);
}

__device__ __forceinline__ unsigned long long pack_best(float sim, int idx) {
    return ((unsigned long long)float_to_ordered(sim) << 32) |
           (unsigned int)(~(unsigned int)idx);   // ~idx: ties -> smaller idx
}

// grid: SIM_BLKS x 256 (4 waves). One wave per row, grid-stride. q fragment
// held in registers (loop-invariant). Block-level reduce -> ONE plain store.
__launch_bounds__(256)
__global__ void sim_kernel(const float* __restrict__ bank, const float* __restrict__ ws,
                           unsigned long long* __restrict__ bests) {
    __shared__ unsigned long long wbest[4];
    int tid  = threadIdx.x;
    int lane = tid & 63;
    int wid  = tid >> 6;

    // hoist q fragment: 4 x float4 per lane, loop-invariant (L2-hit loads)
    const float4* q4 = (const float4*)(ws + WS_Q);
    float4 q0 = q4[lane +   0];
    float4 q1 = q4[lane +  64];
    float4 q2 = q4[lane + 128];
    float4 q3 = q4[lane + 192];
    float qn = ws[WS_QNORM];

    int gw = blockIdx.x * 4 + wid;
    int nw = gridDim.x * 4;

    float bestSim = -1e30f;
    int   bestIdx = 0;

    for (int row = gw; row < NMEM; row += nw) {
        const float4* bp = (const float4*)(bank + (size_t)row * DIM);
        float4 b0 = bp[lane +   0];
        float4 b1 = bp[lane +  64];
        float4 b2 = bp[lane + 128];
        float4 b3 = bp[lane + 192];
        float dot = b0.x*q0.x + b0.y*q0.y + b0.z*q0.z + b0.w*q0.w
                  + b1.x*q1.x + b1.y*q1.y + b1.z*q1.z + b1.w*q1.w
                  + b2.x*q2.x + b2.y*q2.y + b2.z*q2.z + b2.w*q2.w
                  + b3.x*q3.x + b3.y*q3.y + b3.z*q3.z + b3.w*q3.w;
        float ss  = b0.x*b0.x + b0.y*b0.y + b0.z*b0.z + b0.w*b0.w
                  + b1.x*b1.x + b1.y*b1.y + b1.z*b1.z + b1.w*b1.w
                  + b2.x*b2.x + b2.y*b2.y + b2.z*b2.z + b2.w*b2.w
                  + b3.x*b3.x + b3.y*b3.y + b3.z*b3.z + b3.w*b3.w;
        #pragma unroll
        for (int m = 32; m >= 1; m >>= 1) {
            dot += __shfl_xor(dot, m);
            ss  += __shfl_xor(ss, m);
        }
        float bn  = fmaxf(sqrtf(ss), EPS);
        float sim = dot / (bn * qn);
        if (sim > bestSim) { bestSim = sim; bestIdx = row; }
    }
    if (lane == 0) wbest[wid] = pack_best(bestSim, bestIdx);
    __syncthreads();
    if (tid == 0) {
        unsigned long long p = wbest[0];
        if (wbest[1] > p) p = wbest[1];
        if (wbest[2] > p) p = wbest[2];
        if (wbest[3] > p) p = wbest[3];
        bests[blockIdx.x] = p;   // plain store, zero contention
    }
}

// 1 block x 256 threads: tree-reduce bests[2048] -> final slot.
__global__ void bestfinal_kernel(const unsigned long long* __restrict__ bests,
                                 unsigned long long* __restrict__ final_best) {
    __shared__ unsigned long long red[256];
    int tid = threadIdx.x;
    unsigned long long p = bests[tid];
    #pragma unroll
    for (int i = 1; i < SIM_BLKS / 256; ++i) {
        unsigned long long v = bests[tid + i * 256];
        if (v > p) p = v;
    }
    red[tid] = p;
    __syncthreads();
    #pragma unroll
    for (int s = 128; s >= 1; s >>= 1) {
        if (tid < s) {
            if (red[tid + s] > red[tid]) red[tid] = red[tid + s];
        }
        __syncthreads();
    }
    if (tid == 0) *final_best = red[0];
}

// grid: 256 blocks x 256 threads (4 waves). One wave per output row.
__global__ void decode_kernel(const float* __restrict__ bank,
                              const float* __restrict__ w_dec,
                              const float* __restrict__ b_dec,
                              const unsigned long long* __restrict__ best,
                              float* __restrict__ out) {
    __shared__ float mem[DIM];
    int tid = threadIdx.x;

    unsigned long long p = *best;
    unsigned int u = (unsigned int)(p >> 32);
    unsigned int fb = (u & 0x80000000u) ? (u & 0x7FFFFFFFu) : ~u;
    float sim = __uint_as_float(fb);
    int idx   = (int)(~(unsigned int)(p & 0xFFFFFFFFu));

    ((float4*)mem)[tid] = ((const float4*)(bank + (size_t)idx * DIM))[tid];
    __syncthreads();

    bool ok  = sim > THR;
    int lane = tid & 63, wid = tid >> 6;
    int row  = blockIdx.x * 4 + wid;

    const float4* wp = (const float4*)(w_dec + (size_t)row * DIM);
    const float4* m4 = (const float4*)mem;
    float dot = 0.f;
    #pragma unroll
    for (int it = 0; it < 4; ++it) {
        float4 w = wp[lane + it * 64];
        float4 m = m4[lane + it * 64];
        dot += w.x * m.x + w.y * m.y + w.z * m.z + w.w * m.w;
    }
    #pragma unroll
    for (int m = 32; m >= 1; m >>= 1) dot += __shfl_xor(dot, m);

    if (lane == 0) out[row] = ok ? (dot + b_dec[row]) : 0.0f;
}

extern "C" void kernel_launch(void* const* d_in, const int* in_sizes, int n_in,
                              void* d_out, int out_size, void* d_ws, size_t ws_size,
                              hipStream_t stream) {
    const float* query = (const float*)d_in[0];
    const float* bank  = (const float*)d_in[1];
    const float* w_dec = (const float*)d_in[2];
    const float* b_dec = (const float*)d_in[3];
    float* out = (float*)d_out;
    float* ws  = (float*)d_ws;
    unsigned long long* bests      = (unsigned long long*)(ws + WS_BESTS);
    unsigned long long* final_best = (unsigned long long*)(ws + WS_FINAL);

    init_kernel<<<NCOPY, 256, 0, stream>>>(ws);
    qsum_kernel<<<SEQ / 8, 256, 0, stream>>>(query, ws);
    qfinal_kernel<<<1, 256, 0, stream>>>(ws);
    sim_kernel<<<SIM_BLKS, 256, 0, stream>>>(bank, ws, bests);
    bestfinal_kernel<<<1, 256, 0, stream>>>(bests, final_best);
    decode_kernel<<<256, 256, 0, stream>>>(bank, w_dec, b_dec, final_best, out);
}

// Round 4
// 110.622 us; speedup vs baseline: 1.4929x; 1.0109x over previous
//
#include <hip/hip_runtime.h>

#define EPS 1e-8f
#define THR 0.65f

constexpr int DIM  = 1024;
constexpr int SEQ  = 2048;
constexpr int NMEM = 131072;

constexpr int NCOPY    = 8;     // spread copies of the q accumulator
constexpr int SIM_BLKS = 2048;  // sim grid; one best per block
constexpr int ROWS_PER_WAVE = NMEM / (SIM_BLKS * 4);  // 16

typedef float f4 __attribute__((ext_vector_type(4)));  // plain vector type for nontemporal builtins

// ws layout (float indices):
//   [0 .. 8192)        8 copies x 1024 q accumulators
//   [8192 .. 9216)     q mean
//   [9216]             q_norm (clamped)
//   [9218 .. 13314)    bests[2048] as u64 (byte 36872, 8-aligned)
constexpr int WS_Q     = 8192;
constexpr int WS_QNORM = 9216;
constexpr int WS_BESTS = 9218;

__global__ void init_kernel(float* __restrict__ ws) {
    ((float4*)ws)[blockIdx.x * 256 + threadIdx.x] = make_float4(0.f, 0.f, 0.f, 0.f);
}

// grid: 256 blocks x 256 threads. Block b sums rows [8b, 8b+8); thread t owns
// float4 column t. Atomics spread over NCOPY accumulator copies.
__global__ void qsum_kernel(const float* __restrict__ query, float* __restrict__ ws) {
    const float4* q4 = (const float4*)query;   // [SEQ][256]
    int tid = threadIdx.x;
    int r0  = blockIdx.x * 8;
    float4 s = make_float4(0.f, 0.f, 0.f, 0.f);
    #pragma unroll
    for (int r = 0; r < 8; ++r) {
        float4 v = q4[(size_t)(r0 + r) * 256 + tid];
        s.x += v.x; s.y += v.y; s.z += v.z; s.w += v.w;
    }
    float* dst = ws + (blockIdx.x & (NCOPY - 1)) * DIM + tid * 4;
    atomicAdd(dst + 0, s.x);
    atomicAdd(dst + 1, s.y);
    atomicAdd(dst + 2, s.z);
    atomicAdd(dst + 3, s.w);
}

// 1 block x 256 threads: fold copies, divide by SEQ, clamped ||q||.
__global__ void qfinal_kernel(float* __restrict__ ws) {
    __shared__ float red[4];
    int tid = threadIdx.x;
    float4 v = make_float4(0.f, 0.f, 0.f, 0.f);
    #pragma unroll
    for (int c = 0; c < NCOPY; ++c) {
        float4 p = ((float4*)ws)[c * 256 + tid];
        v.x += p.x; v.y += p.y; v.z += p.z; v.w += p.w;
    }
    const float inv = 1.0f / (float)SEQ;
    v.x *= inv; v.y *= inv; v.z *= inv; v.w *= inv;
    ((float4*)(ws + WS_Q))[tid] = v;
    float ss = v.x * v.x + v.y * v.y + v.z * v.z + v.w * v.w;
    #pragma unroll
    for (int m = 32; m >= 1; m >>= 1) ss += __shfl_xor(ss, m);
    int lane = tid & 63, wid = tid >> 6;
    if (lane == 0) red[wid] = ss;
    __syncthreads();
    if (tid == 0) {
        float tot = red[0] + red[1] + red[2] + red[3];
        ws[WS_QNORM] = fmaxf(sqrtf(tot), EPS);
    }
}

__device__ __forceinline__ unsigned int float_to_ordered(float f) {
    unsigned int b = __float_as_uint(f);
    return (b & 0x80000000u) ? ~b : (b | 0x80000000u);
}

__device__ __forceinline__ unsigned long long pack_best(float sim, int idx) {
    return ((unsigned long long)float_to_ordered(sim) << 32) |
           (unsigned int)(~(unsigned int)idx);   // ~idx: ties -> smaller idx
}

// grid: SIM_BLKS x 256 (4 waves). Each wave owns 16 CONSECUTIVE rows (64 KiB).
// Processed in 4-row groups, fully unrolled: up to 16 independent float4
// loads in flight; 8 independent butterfly reduce chains per group.
__launch_bounds__(256, 4)
__global__ void sim_kernel(const float* __restrict__ bank, const float* __restrict__ ws,
                           unsigned long long* __restrict__ bests) {
    __shared__ unsigned long long wbest[4];
    int tid  = threadIdx.x;
    int lane = tid & 63;
    int wid  = tid >> 6;

    // hoist q fragment: 4 x float4 per lane, loop-invariant
    const f4* q4 = (const f4*)(ws + WS_Q);
    f4 q0 = q4[lane +   0];
    f4 q1 = q4[lane +  64];
    f4 q2 = q4[lane + 128];
    f4 q3 = q4[lane + 192];
    float qn = ws[WS_QNORM];

    int gw   = blockIdx.x * 4 + wid;          // global wave id
    int row0 = gw * ROWS_PER_WAVE;            // 16 consecutive rows

    float bestSim = -1e30f;
    int   bestIdx = 0;

    #pragma unroll
    for (int g = 0; g < ROWS_PER_WAVE / 4; ++g) {
        float dot[4], ss[4];
        f4 b[4][4];
        // 16 independent nontemporal loads (read-once data, no L2 allocate)
        #pragma unroll
        for (int r = 0; r < 4; ++r) {
            const f4* bp = (const f4*)(bank + (size_t)(row0 + g * 4 + r) * DIM);
            b[r][0] = __builtin_nontemporal_load(bp + lane +   0);
            b[r][1] = __builtin_nontemporal_load(bp + lane +  64);
            b[r][2] = __builtin_nontemporal_load(bp + lane + 128);
            b[r][3] = __builtin_nontemporal_load(bp + lane + 192);
        }
        #pragma unroll
        for (int r = 0; r < 4; ++r) {
            dot[r] = b[r][0].x*q0.x + b[r][0].y*q0.y + b[r][0].z*q0.z + b[r][0].w*q0.w
                   + b[r][1].x*q1.x + b[r][1].y*q1.y + b[r][1].z*q1.z + b[r][1].w*q1.w
                   + b[r][2].x*q2.x + b[r][2].y*q2.y + b[r][2].z*q2.z + b[r][2].w*q2.w
                   + b[r][3].x*q3.x + b[r][3].y*q3.y + b[r][3].z*q3.z + b[r][3].w*q3.w;
            ss[r]  = b[r][0].x*b[r][0].x + b[r][0].y*b[r][0].y + b[r][0].z*b[r][0].z + b[r][0].w*b[r][0].w
                   + b[r][1].x*b[r][1].x + b[r][1].y*b[r][1].y + b[r][1].z*b[r][1].z + b[r][1].w*b[r][1].w
                   + b[r][2].x*b[r][2].x + b[r][2].y*b[r][2].y + b[r][2].z*b[r][2].z + b[r][2].w*b[r][2].w
                   + b[r][3].x*b[r][3].x + b[r][3].y*b[r][3].y + b[r][3].z*b[r][3].z + b[r][3].w*b[r][3].w;
        }
        // 8 independent butterfly chains
        #pragma unroll
        for (int m = 32; m >= 1; m >>= 1) {
            #pragma unroll
            for (int r = 0; r < 4; ++r) {
                dot[r] += __shfl_xor(dot[r], m);
                ss[r]  += __shfl_xor(ss[r], m);
            }
        }
        #pragma unroll
        for (int r = 0; r < 4; ++r) {
            float bn  = fmaxf(sqrtf(ss[r]), EPS);
            float sim = dot[r] / (bn * qn);
            if (sim > bestSim) { bestSim = sim; bestIdx = row0 + g * 4 + r; }
        }
    }

    if (lane == 0) wbest[wid] = pack_best(bestSim, bestIdx);
    __syncthreads();
    if (tid == 0) {
        unsigned long long p = wbest[0];
        if (wbest[1] > p) p = wbest[1];
        if (wbest[2] > p) p = wbest[2];
        if (wbest[3] > p) p = wbest[3];
        bests[blockIdx.x] = p;   // plain store, zero contention
    }
}

// grid: 256 blocks x 256 threads (4 waves). Each block first reduces
// bests[2048] (L2-resident, redundant per block — no extra kernel), then one
// wave per output row.
__global__ void decode_kernel(const float* __restrict__ bank,
                              const float* __restrict__ w_dec,
                              const float* __restrict__ b_dec,
                              const unsigned long long* __restrict__ bests,
                              float* __restrict__ out) {
    __shared__ unsigned long long red[256];
    __shared__ float mem[DIM];
    int tid = threadIdx.x;

    // 2048 -> 1 reduce inside each block
    unsigned long long p = bests[tid];
    #pragma unroll
    for (int i = 1; i < SIM_BLKS / 256; ++i) {
        unsigned long long v = bests[tid + i * 256];
        if (v > p) p = v;
    }
    red[tid] = p;
    __syncthreads();
    #pragma unroll
    for (int s = 128; s >= 1; s >>= 1) {
        if (tid < s) {
            if (red[tid + s] > red[tid]) red[tid] = red[tid + s];
        }
        __syncthreads();
    }
    p = red[0];
    unsigned int u = (unsigned int)(p >> 32);
    unsigned int fb = (u & 0x80000000u) ? (u & 0x7FFFFFFFu) : ~u;
    float sim = __uint_as_float(fb);
    int idx   = (int)(~(unsigned int)(p & 0xFFFFFFFFu));

    ((float4*)mem)[tid] = ((const float4*)(bank + (size_t)idx * DIM))[tid];
    __syncthreads();

    bool ok  = sim > THR;
    int lane = tid & 63, wid = tid >> 6;
    int row  = blockIdx.x * 4 + wid;

    const float4* wp = (const float4*)(w_dec + (size_t)row * DIM);
    const float4* m4 = (const float4*)mem;
    float dot = 0.f;
    #pragma unroll
    for (int it = 0; it < 4; ++it) {
        float4 w = wp[lane + it * 64];
        float4 m = m4[lane + it * 64];
        dot += w.x * m.x + w.y * m.y + w.z * m.z + w.w * m.w;
    }
    #pragma unroll
    for (int m = 32; m >= 1; m >>= 1) dot += __shfl_xor(dot, m);

    if (lane == 0) out[row] = ok ? (dot + b_dec[row]) : 0.0f;
}

extern "C" void kernel_launch(void* const* d_in, const int* in_sizes, int n_in,
                              void* d_out, int out_size, void* d_ws, size_t ws_size,
                              hipStream_t stream) {
    const float* query = (const float*)d_in[0];
    const float* bank  = (const float*)d_in[1];
    const float* w_dec = (const float*)d_in[2];
    const float* b_dec = (const float*)d_in[3];
    float* out = (float*)d_out;
    float* ws  = (float*)d_ws;
    unsigned long long* bests = (unsigned long long*)(ws + WS_BESTS);

    init_kernel<<<NCOPY, 256, 0, stream>>>(ws);
    qsum_kernel<<<SEQ / 8, 256, 0, stream>>>(query, ws);
    qfinal_kernel<<<1, 256, 0, stream>>>(ws);
    sim_kernel<<<SIM_BLKS, 256, 0, stream>>>(bank, ws, bests);
    decode_kernel<<<256, 256, 0, stream>>>(bank, w_dec, b_dec, bests, out);
}

// Round 5
// 106.312 us; speedup vs baseline: 1.5534x; 1.0405x over previous
//
#include <hip/hip_runtime.h>

#define EPS 1e-8f
#define THR 0.65f

constexpr int DIM  = 1024;
constexpr int SEQ  = 2048;
constexpr int NMEM = 131072;

constexpr int SIM_BLKS = 2048;  // sim grid; one best per block
constexpr int ROWS_PER_WAVE = NMEM / (SIM_BLKS * 4);  // 16

typedef float f4 __attribute__((ext_vector_type(4)));

// ws layout (float indices):
//   [0 .. 262144)        partial[256][1024] row-sums (plain stores, no init)
//   [262144 .. 263168)   q mean [1024]
//   [263168 .. 263176)   ssp[8] per-block sum-sq partials of q
//   [263178 .. 267274)   bests[2048] as u64 (byte 1052712, 8-aligned)
constexpr int WS_Q     = 262144;
constexpr int WS_SSP   = 263168;
constexpr int WS_BESTS = 263178;

// grid: 256 x 256. Block b sums query rows [8b, 8b+8); thread t owns f4-col t.
// Plain store to partial[b] — no init, no atomics.
__global__ void qsumA_kernel(const float* __restrict__ query, float* __restrict__ ws) {
    int t = threadIdx.x;
    int b = blockIdx.x;
    const f4* qp = (const f4*)(query + (size_t)b * 8 * DIM) + t;
    f4 s = qp[0];
    #pragma unroll
    for (int r = 1; r < 8; ++r) s += qp[r * 256];
    ((f4*)ws)[b * 256 + t] = s;
}

// grid: 8 x 256. Block j owns f4-cols [32j, 32j+32): folds 256 partials,
// scales by 1/SEQ, writes q-mean cols + its sum-sq partial ssp[j].
__global__ void qsumB_kernel(float* __restrict__ ws) {
    __shared__ f4 lds[256];
    int t = threadIdx.x;
    int j = blockIdx.x;
    int fc    = 32 * j + (t & 31);
    int chunk = t >> 5;
    const f4* pf = (const f4*)ws;
    f4 s = pf[(32 * chunk) * 256 + fc];
    #pragma unroll
    for (int i = 1; i < 32; ++i) s += pf[(32 * chunk + i) * 256 + fc];
    lds[t] = s;
    __syncthreads();
    if (t < 32) {
        f4 f = lds[t];
        #pragma unroll
        for (int c = 1; c < 8; ++c) f += lds[t + 32 * c];
        f *= (1.0f / (float)SEQ);
        ((f4*)(ws + WS_Q))[32 * j + t] = f;
        float ss = f.x * f.x + f.y * f.y + f.z * f.z + f.w * f.w;
        #pragma unroll
        for (int m = 16; m >= 1; m >>= 1) ss += __shfl_xor(ss, m);
        if (t == 0) ws[WS_SSP + j] = ss;
    }
}

__device__ __forceinline__ unsigned int float_to_ordered(float f) {
    unsigned int b = __float_as_uint(f);
    return (b & 0x80000000u) ? ~b : (b | 0x80000000u);
}

__device__ __forceinline__ unsigned long long pack_best(float sim, int idx) {
    return ((unsigned long long)float_to_ordered(sim) << 32) |
           (unsigned int)(~(unsigned int)idx);   // ~idx: ties -> smaller idx
}

// grid: SIM_BLKS x 256 (4 waves). Each wave owns 16 CONSECUTIVE rows.
// 4-row groups fully unrolled; no occupancy cap so the allocator may
// software-pipeline groups. Computes qn from ssp[0..8) itself.
__launch_bounds__(256)
__global__ void sim_kernel(const float* __restrict__ bank, const float* __restrict__ ws,
                           unsigned long long* __restrict__ bests) {
    __shared__ unsigned long long wbest[4];
    int tid  = threadIdx.x;
    int lane = tid & 63;
    int wid  = tid >> 6;

    // qn from the 8 sum-sq partials (broadcast L2 loads)
    float ssq = ws[WS_SSP + 0];
    #pragma unroll
    for (int j = 1; j < 8; ++j) ssq += ws[WS_SSP + j];
    float qn = fmaxf(sqrtf(ssq), EPS);

    // hoist q fragment: 4 x f4 per lane, loop-invariant
    const f4* q4 = (const f4*)(ws + WS_Q);
    f4 q0 = q4[lane +   0];
    f4 q1 = q4[lane +  64];
    f4 q2 = q4[lane + 128];
    f4 q3 = q4[lane + 192];

    int gw   = blockIdx.x * 4 + wid;
    int row0 = gw * ROWS_PER_WAVE;

    float bestSim = -1e30f;
    int   bestIdx = 0;

    #pragma unroll
    for (int g = 0; g < ROWS_PER_WAVE / 4; ++g) {
        float dot[4], ss[4];
        f4 b[4][4];
        #pragma unroll
        for (int r = 0; r < 4; ++r) {
            const f4* bp = (const f4*)(bank + (size_t)(row0 + g * 4 + r) * DIM);
            b[r][0] = __builtin_nontemporal_load(bp + lane +   0);
            b[r][1] = __builtin_nontemporal_load(bp + lane +  64);
            b[r][2] = __builtin_nontemporal_load(bp + lane + 128);
            b[r][3] = __builtin_nontemporal_load(bp + lane + 192);
        }
        #pragma unroll
        for (int r = 0; r < 4; ++r) {
            dot[r] = b[r][0].x*q0.x + b[r][0].y*q0.y + b[r][0].z*q0.z + b[r][0].w*q0.w
                   + b[r][1].x*q1.x + b[r][1].y*q1.y + b[r][1].z*q1.z + b[r][1].w*q1.w
                   + b[r][2].x*q2.x + b[r][2].y*q2.y + b[r][2].z*q2.z + b[r][2].w*q2.w
                   + b[r][3].x*q3.x + b[r][3].y*q3.y + b[r][3].z*q3.z + b[r][3].w*q3.w;
            ss[r]  = b[r][0].x*b[r][0].x + b[r][0].y*b[r][0].y + b[r][0].z*b[r][0].z + b[r][0].w*b[r][0].w
                   + b[r][1].x*b[r][1].x + b[r][1].y*b[r][1].y + b[r][1].z*b[r][1].z + b[r][1].w*b[r][1].w
                   + b[r][2].x*b[r][2].x + b[r][2].y*b[r][2].y + b[r][2].z*b[r][2].z + b[r][2].w*b[r][2].w
                   + b[r][3].x*b[r][3].x + b[r][3].y*b[r][3].y + b[r][3].z*b[r][3].z + b[r][3].w*b[r][3].w;
        }
        #pragma unroll
        for (int m = 32; m >= 1; m >>= 1) {
            #pragma unroll
            for (int r = 0; r < 4; ++r) {
                dot[r] += __shfl_xor(dot[r], m);
                ss[r]  += __shfl_xor(ss[r], m);
            }
        }
        #pragma unroll
        for (int r = 0; r < 4; ++r) {
            float bn  = fmaxf(sqrtf(ss[r]), EPS);
            float sim = dot[r] / (bn * qn);
            if (sim > bestSim) { bestSim = sim; bestIdx = row0 + g * 4 + r; }
        }
    }

    if (lane == 0) wbest[wid] = pack_best(bestSim, bestIdx);
    __syncthreads();
    if (tid == 0) {
        unsigned long long p = wbest[0];
        if (wbest[1] > p) p = wbest[1];
        if (wbest[2] > p) p = wbest[2];
        if (wbest[3] > p) p = wbest[3];
        bests[blockIdx.x] = p;
    }
}

// grid: 256 x 256 (4 waves). Each block redundantly reduces bests[2048]
// (L2-resident), then one wave per output row of the decode matvec.
__global__ void decode_kernel(const float* __restrict__ bank,
                              const float* __restrict__ w_dec,
                              const float* __restrict__ b_dec,
                              const unsigned long long* __restrict__ bests,
                              float* __restrict__ out) {
    __shared__ unsigned long long red[256];
    __shared__ float mem[DIM];
    int tid = threadIdx.x;

    unsigned long long p = bests[tid];
    #pragma unroll
    for (int i = 1; i < SIM_BLKS / 256; ++i) {
        unsigned long long v = bests[tid + i * 256];
        if (v > p) p = v;
    }
    red[tid] = p;
    __syncthreads();
    #pragma unroll
    for (int s = 128; s >= 1; s >>= 1) {
        if (tid < s) {
            if (red[tid + s] > red[tid]) red[tid] = red[tid + s];
        }
        __syncthreads();
    }
    p = red[0];
    unsigned int u = (unsigned int)(p >> 32);
    unsigned int fb = (u & 0x80000000u) ? (u & 0x7FFFFFFFu) : ~u;
    float sim = __uint_as_float(fb);
    int idx   = (int)(~(unsigned int)(p & 0xFFFFFFFFu));

    ((float4*)mem)[tid] = ((const float4*)(bank + (size_t)idx * DIM))[tid];
    __syncthreads();

    bool ok  = sim > THR;
    int lane = tid & 63, wid = tid >> 6;
    int row  = blockIdx.x * 4 + wid;

    const float4* wp = (const float4*)(w_dec + (size_t)row * DIM);
    const float4* m4 = (const float4*)mem;
    float dot = 0.f;
    #pragma unroll
    for (int it = 0; it < 4; ++it) {
        float4 w = wp[lane + it * 64];
        float4 m = m4[lane + it * 64];
        dot += w.x * m.x + w.y * m.y + w.z * m.z + w.w * m.w;
    }
    #pragma unroll
    for (int m = 32; m >= 1; m >>= 1) dot += __shfl_xor(dot, m);

    if (lane == 0) out[row] = ok ? (dot + b_dec[row]) : 0.0f;
}

extern "C" void kernel_launch(void* const* d_in, const int* in_sizes, int n_in,
                              void* d_out, int out_size, void* d_ws, size_t ws_size,
                              hipStream_t stream) {
    const float* query = (const float*)d_in[0];
    const float* bank  = (const float*)d_in[1];
    const float* w_dec = (const float*)d_in[2];
    const float* b_dec = (const float*)d_in[3];
    float* out = (float*)d_out;
    float* ws  = (float*)d_ws;
    unsigned long long* bests = (unsigned long long*)(ws + WS_BESTS);

    qsumA_kernel<<<256, 256, 0, stream>>>(query, ws);
    qsumB_kernel<<<8, 256, 0, stream>>>(ws);
    sim_kernel<<<SIM_BLKS, 256, 0, stream>>>(bank, ws, bests);
    decode_kernel<<<256, 256, 0, stream>>>(bank, w_dec, b_dec, bests, out);
}